// Round 1
// baseline (153.120 us; speedup 1.0000x reference)
//
#include <hip/hip_runtime.h>

// RandRotate90_3D: per-sample rot90^k (k = koefs[b] in [0,3]) on axes (D,H)
// of [B=16, D=128, H=128, W=128] float32, applied to 3 tensors.
// Closed form of the reference's iterative masked-rot90:
//   k=0: out[i][j] = in[i][j]
//   k=1: out[i][j] = in[j][127-i]
//   k=2: out[i][j] = in[127-i][127-j]
//   k=3: out[i][j] = in[127-j][i]
// W axis untouched -> all accesses are 512B-contiguous rows. Pure gather.

#define NB 16
#define NN 128
#define W4 32                        // 128 floats / 4 per float4
#define PER_TENSOR (NB * NN * NN * W4)   // 2^23 float4 per tensor
#define TOTAL4 (3 * PER_TENSOR)

__global__ __launch_bounds__(256) void rot90_gather_kernel(
    const float4* __restrict__ vol,
    const float4* __restrict__ msk,
    const float4* __restrict__ skl,
    const int* __restrict__ koefs,
    float4* __restrict__ out)
{
    const int stride = gridDim.x * blockDim.x;
    for (int idx = blockIdx.x * blockDim.x + threadIdx.x; idx < TOTAL4; idx += stride) {
        // idx = ((t*16 + b)*128 + i)*128*32 + j*32 + w4 ; per-tensor span = 2^23
        const int t  = idx >> 23;
        const int b  = (idx >> 19) & 15;
        const int i  = (idx >> 12) & 127;
        const int j  = (idx >> 5) & 127;
        const int w4 = idx & 31;

        const int k = koefs[b];   // broadcast, L1/L2-cached
        int si, sj;
        switch (k) {
            case 1:  si = j;        sj = 127 - i; break;
            case 2:  si = 127 - i;  sj = 127 - j; break;
            case 3:  si = 127 - j;  sj = i;       break;
            default: si = i;        sj = j;       break;
        }
        const int src = ((b * NN + si) * NN + sj) * W4 + w4;

        const float4* __restrict__ in = (t == 0) ? vol : (t == 1) ? msk : skl;
        out[idx] = in[src];
    }
}

extern "C" void kernel_launch(void* const* d_in, const int* in_sizes, int n_in,
                              void* d_out, int out_size, void* d_ws, size_t ws_size,
                              hipStream_t stream) {
    const float4* vol = (const float4*)d_in[0];
    const float4* msk = (const float4*)d_in[1];
    const float4* skl = (const float4*)d_in[2];
    const int* koefs  = (const int*)d_in[3];
    float4* out = (float4*)d_out;

    // 2048 blocks x 256 threads, grid-stride (~48 float4 per thread)
    const int blocks = 2048;
    rot90_gather_kernel<<<blocks, 256, 0, stream>>>(vol, msk, skl, koefs, out);
}

// Round 3
// 145.713 us; speedup vs baseline: 1.0508x; 1.0508x over previous
//
#include <hip/hip_runtime.h>

// RandRotate90_3D: per-sample rot90^k (k = koefs[b] in [0,3]) on axes (D,H)
// of [B=16, D=128, H=128, W=128] float32, applied to 3 tensors.
// Closed form of the reference's iterative masked-rot90:
//   k=0: out[i][j] = in[i][j]
//   k=1: out[i][j] = in[j][127-i]
//   k=2: out[i][j] = in[127-i][127-j]
//   k=3: out[i][j] = in[127-j][i]
// W axis untouched -> all accesses are 512B-contiguous rows. Pure gather.
// R3: non-temporal via clang native vector type (R2's HIP_vector_type failed
// to compile) + exact trip count (48/thread) + unroll 4.

typedef float f32x4 __attribute__((ext_vector_type(4)));

#define NB 16
#define NN 128
#define W4 32                            // 128 floats / 4 per float4
#define PER_TENSOR (NB * NN * NN * W4)   // 2^23 float4 per tensor
#define TOTAL4 (3 * PER_TENSOR)          // 25165824
#define BLOCKS 2048
#define TPB 256
#define NTHREADS (BLOCKS * TPB)          // 524288
#define ITERS (TOTAL4 / NTHREADS)        // 48 exactly

__global__ __launch_bounds__(TPB) void rot90_gather_kernel(
    const f32x4* __restrict__ vol,
    const f32x4* __restrict__ msk,
    const f32x4* __restrict__ skl,
    const int* __restrict__ koefs,
    f32x4* __restrict__ out)
{
    int idx = blockIdx.x * TPB + threadIdx.x;
#pragma unroll 4
    for (int it = 0; it < ITERS; ++it, idx += NTHREADS) {
        // idx = ((t*16 + b)*128 + i)*128*32 + j*32 + w4 ; per-tensor span = 2^23
        const int t  = idx >> 23;
        const int b  = (idx >> 19) & 15;
        const int i  = (idx >> 12) & 127;
        const int j  = (idx >> 5) & 127;
        const int w4 = idx & 31;

        const int k = koefs[b];   // wave-uniform (b constant within a wave)
        int si, sj;
        switch (k) {
            case 1:  si = j;        sj = 127 - i; break;
            case 2:  si = 127 - i;  sj = 127 - j; break;
            case 3:  si = 127 - j;  sj = i;       break;
            default: si = i;        sj = j;       break;
        }
        const int src = ((b * NN + si) * NN + sj) * W4 + w4;

        const f32x4* __restrict__ in = (t == 0) ? vol : (t == 1) ? msk : skl;
        const f32x4 v = __builtin_nontemporal_load(&in[src]);
        __builtin_nontemporal_store(v, &out[idx]);
    }
}

extern "C" void kernel_launch(void* const* d_in, const int* in_sizes, int n_in,
                              void* d_out, int out_size, void* d_ws, size_t ws_size,
                              hipStream_t stream) {
    const f32x4* vol = (const f32x4*)d_in[0];
    const f32x4* msk = (const f32x4*)d_in[1];
    const f32x4* skl = (const f32x4*)d_in[2];
    const int* koefs  = (const int*)d_in[3];
    f32x4* out = (f32x4*)d_out;

    rot90_gather_kernel<<<BLOCKS, TPB, 0, stream>>>(vol, msk, skl, koefs, out);
}